// Round 14
// baseline (321.682 us; speedup 1.0000x reference)
//
#include <hip/hip_runtime.h>

// RiskGCN: 3-layer GCNConv (self-loops, sym deg^-1/2 norm) + mean pool + linear head.
// N=100000 nodes, E=1.6M edges, D=128, 256 graphs.
// Build: wsplit3(+gcur zero) -> fused [bucket-scatter || layer-1 GEMM] ->
// k_bucketB2 (per-bucket hist + scan + dinv/row_start + counting-sort -> CSR).
// CSR stores src only; agg computes norm = dinv[src]*dinv[dst] on the fly
// (dinv is 400KB -> L2-resident; scalarized edge loop makes it a scalar load).
// Per layer: MFMA bf16 GEMM (W split hi/lo; async global_load_lds staging) ->
// row-major CSR gather-agg (bf16 msgs, f32 acc). Layer 3 fuses per-node head
// dot; segment reduce finishes mean+bias.

#define D 128
#define NB_SHIFT 8            // 256 nodes per bucket
#define BCAP 8192             // arena stride per bucket; mean 4096, 64 sigma headroom
#define EPB 4096              // edges per block in bucket pass A (391 blocks)
// NOTE: packing assumes N <= 2^17 and nodes-per-bucket <= 256.

typedef unsigned int uint;
typedef unsigned short ushort;
typedef __attribute__((ext_vector_type(8))) short short8;
typedef __attribute__((ext_vector_type(4))) float f32x4;

__device__ __forceinline__ ushort f2bf(float f) {
    uint u = __float_as_uint(f);
    uint r = (u + 0x7fffu + ((u >> 16) & 1u)) >> 16;   // RNE
    return (ushort)r;
}
__device__ __forceinline__ float bf2f(ushort b) {
    return __uint_as_float(((uint)b) << 16);
}

// async 16B global->LDS copy (lds dest is wave-uniform base; HW adds lane*16)
__device__ __forceinline__ void async_cp16(const ushort* g, ushort* lds_uniform) {
    __builtin_amdgcn_global_load_lds(
        (const __attribute__((address_space(1))) unsigned int*)g,
        (__attribute__((address_space(3))) unsigned int*)lds_uniform,
        16, 0, 0);
}

// ---------------- bucket scatter body (pass A) ----------------
// Entry: (dlocal << 17) | src.
__device__ __forceinline__ void bucketA_body(const int* __restrict__ src,
                                             const int* __restrict__ dst, int E,
                                             int nbk, int* __restrict__ gcur,
                                             uint* __restrict__ arena, int bid,
                                             int* hist, int* rbase) {
    int t = threadIdx.x;
    int e0 = bid * EPB;
    int e1 = min(e0 + EPB, E);
    for (int i = t; i < nbk; i += 256) hist[i] = 0;
    __syncthreads();
    for (int e = e0 + t; e < e1; e += 256)
        atomicAdd(&hist[dst[e] >> NB_SHIFT], 1);
    __syncthreads();
    for (int i = t; i < nbk; i += 256) {
        int c = hist[i];
        rbase[i] = (c > 0) ? atomicAdd(&gcur[i], c) : 0;
        hist[i] = 0;   // reuse as local cursor
    }
    __syncthreads();
    for (int e = e0 + t; e < e1; e += 256) {
        int d = dst[e];
        int s = src[e];
        int b = d >> NB_SHIFT;
        int pos = rbase[b] + atomicAdd(&hist[b], 1);
        if (pos < BCAP)
            arena[(size_t)b * BCAP + pos] =
                ((uint)(d & ((1 << NB_SHIFT) - 1)) << 17) | (uint)s;
    }
}

// ---------------- MFMA GEMM body: T_bf16[rowb..rowb+64) = A @ W ----------------
template <bool AF32>
__device__ __forceinline__ void gemm_body(const void* __restrict__ Ain,
                                          const ushort* __restrict__ Wf,
                                          ushort* __restrict__ out, int N,
                                          int rowb, ushort* As) {
    int t = threadIdx.x;

    if (AF32) {
        const float* A = (const float*)Ain;
#pragma unroll
        for (int i = 0; i < 8; i++) {
            int u = i * 256 + t;
            int row = u >> 5, c4 = u & 31;
            int grow = rowb + row;
            float4 v = make_float4(0.f, 0.f, 0.f, 0.f);
            if (grow < N) v = *(const float4*)(A + (size_t)grow * D + c4 * 4);
            uint2 p;
            p.x = (uint)f2bf(v.x) | ((uint)f2bf(v.y) << 16);
            p.y = (uint)f2bf(v.z) | ((uint)f2bf(v.w) << 16);
            int byteoff = row * 256 + ((c4 * 8) ^ ((row & 7) << 4));
            *(uint2*)((char*)As + byteoff) = p;
        }
    } else {
        const ushort* A = (const ushort*)Ain;
        // chunk u = (row=u>>4, c'=u&15); source chunk c = c' ^ (row&7).
#pragma unroll
        for (int i = 0; i < 4; i++) {
            int u = i * 256 + t;
            int row = u >> 4, cp = u & 15;
            int grow = rowb + row;
            if (grow >= N) grow = N - 1;          // clamp; rows discarded at store
            int gc = cp ^ (row & 7);
            const ushort* gp = A + (size_t)grow * D + gc * 8;
            ushort* lb = As + (size_t)(i * 256 + (t & 192)) * 8;
            async_cp16(gp, lb);
        }
        asm volatile("s_waitcnt vmcnt(0)" ::: "memory");
    }
    __syncthreads();

    int wave = t >> 6, lane = t & 63;
    const short8* Wf8 = (const short8*)Wf;

    short8 bhi[2][4], blo[2][4];
#pragma unroll
    for (int j = 0; j < 2; j++) {
        int nt = wave * 2 + j;
#pragma unroll
        for (int kt = 0; kt < 4; kt++) {
            bhi[j][kt] = Wf8[(size_t)((0 * 4 + kt) * 8 + nt) * 64 + lane];
            blo[j][kt] = Wf8[(size_t)((1 * 4 + kt) * 8 + nt) * 64 + lane];
        }
    }

    f32x4 acc[4][2];
#pragma unroll
    for (int m = 0; m < 4; m++)
#pragma unroll
        for (int j = 0; j < 2; j++) acc[m][j] = (f32x4){0.f, 0.f, 0.f, 0.f};

#pragma unroll
    for (int m = 0; m < 4; m++) {
        int r = m * 16 + (lane & 15);
#pragma unroll
        for (int kt = 0; kt < 4; kt++) {
            int raw = kt * 64 + (lane >> 4) * 16;
            short8 a = *(const short8*)((const char*)As + r * 256 + (raw ^ ((r & 7) << 4)));
#pragma unroll
            for (int j = 0; j < 2; j++) {
                acc[m][j] = __builtin_amdgcn_mfma_f32_16x16x32_bf16(a, bhi[j][kt], acc[m][j], 0, 0, 0);
                acc[m][j] = __builtin_amdgcn_mfma_f32_16x16x32_bf16(a, blo[j][kt], acc[m][j], 0, 0, 0);
            }
        }
    }

    // C/D: col = lane&15, row = (lane>>4)*4 + jj
#pragma unroll
    for (int m = 0; m < 4; m++) {
#pragma unroll
        for (int j = 0; j < 2; j++) {
            int colb = (wave * 2 + j) * 16 + (lane & 15);
#pragma unroll
            for (int jj = 0; jj < 4; jj++) {
                int grow = rowb + m * 16 + (lane >> 4) * 4 + jj;
                if (grow < N)
                    out[(size_t)grow * D + colb] = f2bf(acc[m][j][jj]);
            }
        }
    }
}

// ---------------- fused: bucket scatter (blocks 0..nA) || layer-1 GEMM ----------------
__global__ __launch_bounds__(256) void k_build_gemm1(const int* __restrict__ src,
                                                     const int* __restrict__ dst, int E,
                                                     int nbk, int* __restrict__ gcur,
                                                     uint* __restrict__ arena, int nA,
                                                     const float* __restrict__ x,
                                                     const ushort* __restrict__ Wf,
                                                     ushort* __restrict__ T, int N) {
    __shared__ ushort As[64 * D];   // 16 KB; bucketA aliases first 4 KB
    if ((int)blockIdx.x < nA) {
        int* hist = (int*)As;
        int* rbase = hist + 512;
        bucketA_body(src, dst, E, nbk, gcur, arena, blockIdx.x, hist, rbase);
    } else {
        gemm_body<true>(x, Wf, T, N, (blockIdx.x - nA) * 64, As);
    }
}

// ---------------- standalone GEMM (layers 2-3) ----------------
template <bool AF32>
__global__ __launch_bounds__(256) void k_gemm(const void* __restrict__ Ain,
                                              const ushort* __restrict__ Wf,
                                              ushort* __restrict__ out, int N) {
    __shared__ ushort As[64 * D];
    gemm_body<AF32>(Ain, Wf, out, N, blockIdx.x * 64, As);
}

// ---------------- fused hist + scan + dinv/row_start + counting-sort -> CSR ----------------
// One block per bucket. Bucket base = prefix of gcur computed in-block.
// CSR entry = src node id (norm computed in agg from dinv).
__global__ __launch_bounds__(256) void k_bucketB2(const uint* __restrict__ arena,
                                                  const int* __restrict__ gcur,
                                                  int nbk, int N, int E,
                                                  float* __restrict__ dinv,
                                                  int* __restrict__ row_start,
                                                  uint* __restrict__ csr) {
    int b = blockIdx.x;
    int t = threadIdx.x;
    __shared__ int hist[256];
    __shared__ int sc[256];
    __shared__ uint sout[BCAP];   // 32 KB; also reduce scratch before sort
    hist[t] = 0;
    __syncthreads();
    int cnt = min(gcur[b], BCAP);
    const uint* seg = arena + (size_t)b * BCAP;
    for (int i = t; i < cnt; i += 256)
        atomicAdd(&hist[seg[i] >> 17], 1);

    // bucket base: sum gcur[0..b) via sout scratch (nbk <= 512)
    int p = 0;
    if (t < b) p += gcur[t];
    if (t + 256 < b) p += gcur[t + 256];
    ((int*)sout)[t] = p;
    __syncthreads();                       // also covers hist atomics
    for (int off2 = 128; off2 > 0; off2 >>= 1) {
        if (t < off2) ((int*)sout)[t] += ((int*)sout)[t + off2];
        __syncthreads();
    }
    int bbase = ((int*)sout)[0];

    // within-bucket exclusive scan of per-node degree
    int c = hist[t];
    sc[t] = c;
    __syncthreads();
    for (int off2 = 1; off2 < 256; off2 <<= 1) {
        int x = (t >= off2) ? sc[t - off2] : 0;
        __syncthreads();
        sc[t] += x;
        __syncthreads();
    }
    int excl = sc[t] - c;

    int node = (b << NB_SHIFT) + t;
    if (node < N) {
        dinv[node] = rsqrtf((float)(c + 1));   // +1 self-loop
        row_start[node] = bbase + excl;
    }
    if (b == 0 && t == 0) row_start[N] = E;

    // counting sort into LDS image, then coalesced CSR write
    sc[t] = excl;
    hist[t] = 0;
    __syncthreads();
    for (int i = t; i < cnt; i += 256) {
        uint en = seg[i];
        int dl = en >> 17;
        int pos = atomicAdd(&hist[dl], 1);
        sout[sc[dl] + pos] = en & 0x1FFFF;     // src only
    }
    __syncthreads();
    for (int i = t; i < cnt; i += 256)
        csr[bbase + i] = sout[i];
}

// ---------------- W split+fragment for all 3 layers (+ gcur zero) ----------------
__global__ void k_wsplit3(const float* __restrict__ W1, const float* __restrict__ W2,
                          const float* __restrict__ W3, ushort* __restrict__ Wf,
                          int* __restrict__ gcur, int nbk) {
    int gidx = blockIdx.x * blockDim.x + threadIdx.x;   // 98304 total
    if (gidx < nbk) gcur[gidx] = 0;
    if (gidx >= 3 * 32768) return;
    int which = gidx >> 15;
    int idx = gidx & 32767;
    const float* W = (which == 0) ? W1 : (which == 1) ? W2 : W3;
    int i  = idx & 7;
    int l  = (idx >> 3) & 63;
    int nt = (idx >> 9) & 7;
    int kt = (idx >> 12) & 3;
    int h  = idx >> 14;
    int k = kt * 32 + (l >> 4) * 8 + i;
    int n = nt * 16 + (l & 15);
    float w = W[k * D + n];
    ushort hi = f2bf(w);
    ushort v = (h == 0) ? hi : f2bf(w - bf2f(hi));
    Wf[gidx] = v;
}

// ---------------- scalarized node aggregation core ----------------
// One wave per node, lane covers 2 cols. 16 csr entries fetched by one vector
// load (lanes 0-15); per-edge dinv[src] is a uniform L2-hit load; norm = ds*di.
__device__ __forceinline__ void agg_core(const ushort* __restrict__ T,
                                         const uint* __restrict__ csr,
                                         const float* __restrict__ dinv,
                                         float di, int beg, int end, int col,
                                         float& a0, float& a1) {
    if (beg >= end) return;
    int lane16 = threadIdx.x & 15;
    uint cur = csr[min(beg + lane16, end - 1)];
    for (int e = beg; e < end; e += 16) {
        uint nxt = 0;
        int en = e + 16;
        if (en < end) nxt = csr[min(en + lane16, end - 1)];
        uint v[16];
        float nn[16];
#pragma unroll
        for (int q = 0; q < 16; q++) {
            uint c = __builtin_amdgcn_readlane(cur, q);
            float ds = dinv[c];
            nn[q] = (e + q < end) ? ds * di : 0.f;
            v[q] = *(const uint*)(T + (size_t)c * D + col);
        }
#pragma unroll
        for (int q = 0; q < 16; q++) {
            a0 = fmaf(nn[q], __uint_as_float(v[q] << 16), a0);
            a1 = fmaf(nn[q], __uint_as_float(v[q] & 0xffff0000u), a1);
        }
        cur = nxt;
    }
}

// ---------------- aggregation: Hbf[i] = relu( sum_j nrm*T[j] + di^2*T[i] + b ) ----------------
__global__ __launch_bounds__(256) void k_agg(const ushort* __restrict__ T,
                                             const float* __restrict__ dinv,
                                             const int* __restrict__ row_start,
                                             const uint* __restrict__ csr,
                                             const float* __restrict__ bias,
                                             ushort* __restrict__ out, int N) {
    int node = __builtin_amdgcn_readfirstlane(blockIdx.x * 4 + (threadIdx.x >> 6));
    if (node >= N) return;
    int lane = threadIdx.x & 63;
    int col = lane * 2;

    float di = dinv[node];
    uint vs = *(const uint*)(T + (size_t)node * D + col);
    float sw = di * di;
    float a0 = sw * __uint_as_float(vs << 16);
    float a1 = sw * __uint_as_float(vs & 0xffff0000u);

    agg_core(T, csr, dinv, di, row_start[node], row_start[node + 1], col, a0, a1);

    a0 = fmaxf(a0 + bias[col], 0.f);
    a1 = fmaxf(a1 + bias[col + 1], 0.f);
    ushort2 o; o.x = f2bf(a0); o.y = f2bf(a1);
    *(ushort2*)(out + (size_t)node * D + col) = o;
}

// ---------------- layer-3 aggregation + per-node head dot (no atomics) ----------------
__global__ __launch_bounds__(256) void k_agg_head(const ushort* __restrict__ T,
                                                  const float* __restrict__ dinv,
                                                  const int* __restrict__ row_start,
                                                  const uint* __restrict__ csr,
                                                  const float* __restrict__ bias,
                                                  const float* __restrict__ Wh,
                                                  float2* __restrict__ y, int N) {
    int node = __builtin_amdgcn_readfirstlane(blockIdx.x * 4 + (threadIdx.x >> 6));
    if (node >= N) return;
    int lane = threadIdx.x & 63;
    int col = lane * 2;

    float di = dinv[node];
    uint vs = *(const uint*)(T + (size_t)node * D + col);
    float sw = di * di;
    float a0 = sw * __uint_as_float(vs << 16);
    float a1 = sw * __uint_as_float(vs & 0xffff0000u);

    agg_core(T, csr, dinv, di, row_start[node], row_start[node + 1], col, a0, a1);

    a0 = fmaxf(a0 + bias[col], 0.f);
    a1 = fmaxf(a1 + bias[col + 1], 0.f);

    float p0 = a0 * Wh[col * 2 + 0] + a1 * Wh[(col + 1) * 2 + 0];
    float p1 = a0 * Wh[col * 2 + 1] + a1 * Wh[(col + 1) * 2 + 1];
#pragma unroll
    for (int off = 32; off > 0; off >>= 1) {
        p0 += __shfl_xor(p0, off);
        p1 += __shfl_xor(p1, off);
    }
    if (lane == 0) y[node] = make_float2(p0, p1);
}

// ---------------- per-graph segment mean + bias (batch sorted) ----------------
__global__ __launch_bounds__(256) void k_pool2(const float2* __restrict__ y,
                                               const int* __restrict__ batch, int N,
                                               const float* __restrict__ bh,
                                               float* __restrict__ out) {
    int g = blockIdx.x;
    int t = threadIdx.x;
    int lo = 0, hi = N;
    while (lo < hi) { int m = (lo + hi) >> 1; if (batch[m] < g) lo = m + 1; else hi = m; }
    int beg = lo;
    lo = 0; hi = N;
    while (lo < hi) { int m = (lo + hi) >> 1; if (batch[m] < g + 1) lo = m + 1; else hi = m; }
    int endi = lo;

    float s0 = 0.f, s1 = 0.f;
    for (int i = beg + t; i < endi; i += 256) {
        float2 v = y[i];
        s0 += v.x; s1 += v.y;
    }
    __shared__ float r0[256], r1[256];
    r0[t] = s0; r1[t] = s1;
    __syncthreads();
    for (int off = 128; off > 0; off >>= 1) {
        if (t < off) { r0[t] += r0[t + off]; r1[t] += r1[t + off]; }
        __syncthreads();
    }
    if (t == 0) {
        float cnt = (float)((endi - beg) > 0 ? (endi - beg) : 1);
        out[g * 2 + 0] = r0[0] / cnt + bh[0];
        out[g * 2 + 1] = r1[0] / cnt + bh[1];
    }
}

extern "C" void kernel_launch(void* const* d_in, const int* in_sizes, int n_in,
                              void* d_out, int out_size, void* d_ws, size_t ws_size,
                              hipStream_t stream) {
    const float* x   = (const float*)d_in[0];
    const int* eidx  = (const int*)d_in[1];
    const int* batch = (const int*)d_in[2];
    const float* W1 = (const float*)d_in[3];
    const float* b1 = (const float*)d_in[4];
    const float* W2 = (const float*)d_in[5];
    const float* b2 = (const float*)d_in[6];
    const float* W3 = (const float*)d_in[7];
    const float* b3 = (const float*)d_in[8];
    const float* Wh = (const float*)d_in[9];
    const float* bh = (const float*)d_in[10];

    int E = in_sizes[1] / 2;
    int N = in_sizes[2];
    int ngraphs = out_size / 2;
    const int* src = eidx;
    const int* dst = eidx + E;
    int nbk = (N + (1 << NB_SHIFT) - 1) >> NB_SHIFT;

    char* ws = (char*)d_ws;
    size_t off = 0;
    auto alloc = [&](size_t bytes) -> void* {
        void* p = ws + off;
        off = (off + bytes + 255) & ~(size_t)255;
        return p;
    };
    ushort* Hbf      = (ushort*)alloc((size_t)N * D * 2);
    ushort* T        = (ushort*)alloc((size_t)N * D * 2);
    ushort* Wf       = (ushort*)alloc(3 * 32768 * 2);
    float*  dinv     = (float*)alloc((size_t)N * 4);
    int*    row_start= (int*)alloc((size_t)(N + 1) * 4);
    int*    gcur     = (int*)alloc((size_t)nbk * 4);
    float2* y        = (float2*)alloc((size_t)N * 8);
    uint*   csr      = (uint*)alloc((size_t)E * 4);
    uint*   arena    = (uint*)alloc((size_t)nbk * BCAP * 4);
    (void)ws_size;

    k_wsplit3<<<384, 256, 0, stream>>>(W1, W2, W3, Wf, gcur, nbk);

    int gemm_grid = (N + 63) / 64;
    int agg_grid = (N + 3) / 4;
    int nA = (E + EPB - 1) / EPB;

    // fused: CSR bucket scatter (first nA blocks) || layer-1 GEMM
    k_build_gemm1<<<nA + gemm_grid, 256, 0, stream>>>(src, dst, E, nbk, gcur, arena,
                                                      nA, x, Wf, T, N);
    k_bucketB2<<<nbk, 256, 0, stream>>>(arena, gcur, nbk, N, E, dinv, row_start, csr);

    // layer 1 aggregation
    k_agg<<<agg_grid, 256, 0, stream>>>(T, dinv, row_start, csr, b1, Hbf, N);
    // layer 2
    k_gemm<false><<<gemm_grid, 256, 0, stream>>>(Hbf, Wf + 32768, T, N);
    k_agg<<<agg_grid, 256, 0, stream>>>(T, dinv, row_start, csr, b2, Hbf, N);
    // layer 3
    k_gemm<false><<<gemm_grid, 256, 0, stream>>>(Hbf, Wf + 65536, T, N);
    k_agg_head<<<agg_grid, 256, 0, stream>>>(T, dinv, row_start, csr, b3, Wh, y, N);
    k_pool2<<<ngraphs, 256, 0, stream>>>(y, batch, N, bh, (float*)d_out);
}

// Round 15
// 282.519 us; speedup vs baseline: 1.1386x; 1.1386x over previous
//
#include <hip/hip_runtime.h>

// RiskGCN: 3-layer GCNConv (self-loops, sym deg^-1/2 norm) + mean pool + linear head.
// N=100000 nodes, E=1.6M edges, D=128, 256 graphs.
// Build: wsplit3(+gcur zero) -> fused [bucket-scatter || layer-1 GEMM] ->
// k_degB3 (hist + in-block bucket-base prefix + dinv/row_start) ->
// k_bucketB (counting-sort, CSR entry = src<<15 | q15(norm)).
// Per layer: MFMA bf16 GEMM (W split hi/lo; async global_load_lds staging) ->
// row-major CSR gather-agg (bf16 msgs, f32 acc, scalarized 16-deep edge loop).
// Layer 3 fuses per-node head dot; segment reduce finishes mean+bias.

#define D 128
#define NB_SHIFT 8            // 256 nodes per bucket
#define BCAP 8192             // arena stride per bucket; mean 4096, 64 sigma headroom
#define EPB 4096              // edges per block in bucket pass A (391 blocks)
// NOTE: packing assumes N <= 2^17 and nodes-per-bucket <= 256.

typedef unsigned int uint;
typedef unsigned short ushort;
typedef __attribute__((ext_vector_type(8))) short short8;
typedef __attribute__((ext_vector_type(4))) float f32x4;

__device__ __forceinline__ ushort f2bf(float f) {
    uint u = __float_as_uint(f);
    uint r = (u + 0x7fffu + ((u >> 16) & 1u)) >> 16;   // RNE
    return (ushort)r;
}
__device__ __forceinline__ float bf2f(ushort b) {
    return __uint_as_float(((uint)b) << 16);
}
// 15-bit float norm decode: 5 LSBs of exponent + 10 mantissa bits, exp base 96.
__device__ __forceinline__ float q15f(uint q) {
    return __uint_as_float(0x30000000u | (q << 13));
}

// async 16B global->LDS copy (lds dest is wave-uniform base; HW adds lane*16)
__device__ __forceinline__ void async_cp16(const ushort* g, ushort* lds_uniform) {
    __builtin_amdgcn_global_load_lds(
        (const __attribute__((address_space(1))) unsigned int*)g,
        (__attribute__((address_space(3))) unsigned int*)lds_uniform,
        16, 0, 0);
}

// ---------------- bucket scatter body (pass A) ----------------
// Entry: (dlocal << 17) | src.
__device__ __forceinline__ void bucketA_body(const int* __restrict__ src,
                                             const int* __restrict__ dst, int E,
                                             int nbk, int* __restrict__ gcur,
                                             uint* __restrict__ arena, int bid,
                                             int* hist, int* rbase) {
    int t = threadIdx.x;
    int e0 = bid * EPB;
    int e1 = min(e0 + EPB, E);
    for (int i = t; i < nbk; i += 256) hist[i] = 0;
    __syncthreads();
    for (int e = e0 + t; e < e1; e += 256)
        atomicAdd(&hist[dst[e] >> NB_SHIFT], 1);
    __syncthreads();
    for (int i = t; i < nbk; i += 256) {
        int c = hist[i];
        rbase[i] = (c > 0) ? atomicAdd(&gcur[i], c) : 0;
        hist[i] = 0;   // reuse as local cursor
    }
    __syncthreads();
    for (int e = e0 + t; e < e1; e += 256) {
        int d = dst[e];
        int s = src[e];
        int b = d >> NB_SHIFT;
        int pos = rbase[b] + atomicAdd(&hist[b], 1);
        if (pos < BCAP)
            arena[(size_t)b * BCAP + pos] =
                ((uint)(d & ((1 << NB_SHIFT) - 1)) << 17) | (uint)s;
    }
}

// ---------------- MFMA GEMM body: T_bf16[rowb..rowb+64) = A @ W ----------------
template <bool AF32>
__device__ __forceinline__ void gemm_body(const void* __restrict__ Ain,
                                          const ushort* __restrict__ Wf,
                                          ushort* __restrict__ out, int N,
                                          int rowb, ushort* As) {
    int t = threadIdx.x;

    if (AF32) {
        const float* A = (const float*)Ain;
#pragma unroll
        for (int i = 0; i < 8; i++) {
            int u = i * 256 + t;
            int row = u >> 5, c4 = u & 31;
            int grow = rowb + row;
            float4 v = make_float4(0.f, 0.f, 0.f, 0.f);
            if (grow < N) v = *(const float4*)(A + (size_t)grow * D + c4 * 4);
            uint2 p;
            p.x = (uint)f2bf(v.x) | ((uint)f2bf(v.y) << 16);
            p.y = (uint)f2bf(v.z) | ((uint)f2bf(v.w) << 16);
            int byteoff = row * 256 + ((c4 * 8) ^ ((row & 7) << 4));
            *(uint2*)((char*)As + byteoff) = p;
        }
    } else {
        const ushort* A = (const ushort*)Ain;
        // chunk u = (row=u>>4, c'=u&15); source chunk c = c' ^ (row&7).
#pragma unroll
        for (int i = 0; i < 4; i++) {
            int u = i * 256 + t;
            int row = u >> 4, cp = u & 15;
            int grow = rowb + row;
            if (grow >= N) grow = N - 1;          // clamp; rows discarded at store
            int gc = cp ^ (row & 7);
            const ushort* gp = A + (size_t)grow * D + gc * 8;
            ushort* lb = As + (size_t)(i * 256 + (t & 192)) * 8;
            async_cp16(gp, lb);
        }
        asm volatile("s_waitcnt vmcnt(0)" ::: "memory");
    }
    __syncthreads();

    int wave = t >> 6, lane = t & 63;
    const short8* Wf8 = (const short8*)Wf;

    short8 bhi[2][4], blo[2][4];
#pragma unroll
    for (int j = 0; j < 2; j++) {
        int nt = wave * 2 + j;
#pragma unroll
        for (int kt = 0; kt < 4; kt++) {
            bhi[j][kt] = Wf8[(size_t)((0 * 4 + kt) * 8 + nt) * 64 + lane];
            blo[j][kt] = Wf8[(size_t)((1 * 4 + kt) * 8 + nt) * 64 + lane];
        }
    }

    f32x4 acc[4][2];
#pragma unroll
    for (int m = 0; m < 4; m++)
#pragma unroll
        for (int j = 0; j < 2; j++) acc[m][j] = (f32x4){0.f, 0.f, 0.f, 0.f};

#pragma unroll
    for (int m = 0; m < 4; m++) {
        int r = m * 16 + (lane & 15);
#pragma unroll
        for (int kt = 0; kt < 4; kt++) {
            int raw = kt * 64 + (lane >> 4) * 16;
            short8 a = *(const short8*)((const char*)As + r * 256 + (raw ^ ((r & 7) << 4)));
#pragma unroll
            for (int j = 0; j < 2; j++) {
                acc[m][j] = __builtin_amdgcn_mfma_f32_16x16x32_bf16(a, bhi[j][kt], acc[m][j], 0, 0, 0);
                acc[m][j] = __builtin_amdgcn_mfma_f32_16x16x32_bf16(a, blo[j][kt], acc[m][j], 0, 0, 0);
            }
        }
    }

    // C/D: col = lane&15, row = (lane>>4)*4 + jj
#pragma unroll
    for (int m = 0; m < 4; m++) {
#pragma unroll
        for (int j = 0; j < 2; j++) {
            int colb = (wave * 2 + j) * 16 + (lane & 15);
#pragma unroll
            for (int jj = 0; jj < 4; jj++) {
                int grow = rowb + m * 16 + (lane >> 4) * 4 + jj;
                if (grow < N)
                    out[(size_t)grow * D + colb] = f2bf(acc[m][j][jj]);
            }
        }
    }
}

// ---------------- fused: bucket scatter (blocks 0..nA) || layer-1 GEMM ----------------
__global__ __launch_bounds__(256) void k_build_gemm1(const int* __restrict__ src,
                                                     const int* __restrict__ dst, int E,
                                                     int nbk, int* __restrict__ gcur,
                                                     uint* __restrict__ arena, int nA,
                                                     const float* __restrict__ x,
                                                     const ushort* __restrict__ Wf,
                                                     ushort* __restrict__ T, int N) {
    __shared__ ushort As[64 * D];   // 16 KB; bucketA aliases first 4 KB
    if ((int)blockIdx.x < nA) {
        int* hist = (int*)As;
        int* rbase = hist + 512;
        bucketA_body(src, dst, E, nbk, gcur, arena, blockIdx.x, hist, rbase);
    } else {
        gemm_body<true>(x, Wf, T, N, (blockIdx.x - nA) * 64, As);
    }
}

// ---------------- standalone GEMM (layers 2-3) ----------------
template <bool AF32>
__global__ __launch_bounds__(256) void k_gemm(const void* __restrict__ Ain,
                                              const ushort* __restrict__ Wf,
                                              ushort* __restrict__ out, int N) {
    __shared__ ushort As[64 * D];
    gemm_body<AF32>(Ain, Wf, out, N, blockIdx.x * 64, As);
}

// ---------------- per-bucket hist + in-block bucket base + dinv/row_start ----------------
__global__ __launch_bounds__(256) void k_degB3(const uint* __restrict__ arena,
                                               const int* __restrict__ gcur,
                                               int nbk, int N, int E,
                                               float* __restrict__ dinv,
                                               int* __restrict__ row_start) {
    int b = blockIdx.x;
    int t = threadIdx.x;
    __shared__ int hist[256];
    __shared__ int sc[256];
    __shared__ int red[256];
    hist[t] = 0;
    __syncthreads();
    int cnt = min(gcur[b], BCAP);
    const uint* seg = arena + (size_t)b * BCAP;
    for (int i = t; i < cnt; i += 256)
        atomicAdd(&hist[seg[i] >> 17], 1);

    // bucket base: sum gcur[0..b)  (nbk <= 512)
    int p = 0;
    if (t < b) p += gcur[t];
    if (t + 256 < b) p += gcur[t + 256];
    red[t] = p;
    __syncthreads();                       // also covers hist atomics
    for (int off2 = 128; off2 > 0; off2 >>= 1) {
        if (t < off2) red[t] += red[t + off2];
        __syncthreads();
    }
    int bbase = red[0];

    // within-bucket exclusive scan of per-node degree
    int c = hist[t];
    sc[t] = c;
    __syncthreads();
    for (int off2 = 1; off2 < 256; off2 <<= 1) {
        int x = (t >= off2) ? sc[t - off2] : 0;
        __syncthreads();
        sc[t] += x;
        __syncthreads();
    }
    int node = (b << NB_SHIFT) + t;
    if (node < N) {
        dinv[node] = rsqrtf((float)(c + 1));      // +1 self-loop
        row_start[node] = bbase + sc[t] - c;
    }
    if (b == 0 && t == 0) row_start[N] = E;
}

// ---------------- bucket pass B: counting-sort bucket into CSR via LDS ----------------
// CSR entry: (src << 15) | q15(norm).
__global__ __launch_bounds__(256) void k_bucketB(const uint* __restrict__ arena,
                                                 const int* __restrict__ gcur,
                                                 const int* __restrict__ row_start,
                                                 const float* __restrict__ dinv,
                                                 int N, uint* __restrict__ csr) {
    int b = blockIdx.x;
    int t = threadIdx.x;
    int n0 = b << NB_SHIFT;
    int nn = min(1 << NB_SHIFT, N - n0);
    __shared__ float sdinv[256];
    __shared__ int sstart[256];
    __shared__ int scur[256];
    __shared__ uint sout[BCAP];   // 32 KB
    for (int i = t; i < nn; i += 256) {
        sdinv[i]  = dinv[n0 + i];
        sstart[i] = row_start[n0 + i];
        scur[i]   = 0;
    }
    __syncthreads();
    int cnt = min(gcur[b], BCAP);
    int csr0 = sstart[0];
    for (int i = t; i < cnt; i += 256) {
        uint en = arena[(size_t)b * BCAP + i];
        int dl = en >> 17;
        int s  = en & 0x1FFFF;
        float nrm = dinv[s] * sdinv[dl];
        uint q = ((__float_as_uint(nrm) + 0x1000u) >> 13) & 0x7FFFu;
        int pos = atomicAdd(&scur[dl], 1);
        sout[(sstart[dl] - csr0) + pos] = ((uint)s << 15) | q;
    }
    __syncthreads();
    for (int i = t; i < cnt; i += 256)
        csr[csr0 + i] = sout[i];
}

// ---------------- W split+fragment for all 3 layers (+ gcur zero) ----------------
__global__ void k_wsplit3(const float* __restrict__ W1, const float* __restrict__ W2,
                          const float* __restrict__ W3, ushort* __restrict__ Wf,
                          int* __restrict__ gcur, int nbk) {
    int gidx = blockIdx.x * blockDim.x + threadIdx.x;   // 98304 total
    if (gidx < nbk) gcur[gidx] = 0;
    if (gidx >= 3 * 32768) return;
    int which = gidx >> 15;
    int idx = gidx & 32767;
    const float* W = (which == 0) ? W1 : (which == 1) ? W2 : W3;
    int i  = idx & 7;
    int l  = (idx >> 3) & 63;
    int nt = (idx >> 9) & 7;
    int kt = (idx >> 12) & 3;
    int h  = idx >> 14;
    int k = kt * 32 + (l >> 4) * 8 + i;
    int n = nt * 16 + (l & 15);
    float w = W[k * D + n];
    ushort hi = f2bf(w);
    ushort v = (h == 0) ? hi : f2bf(w - bf2f(hi));
    Wf[gidx] = v;
}

// ---------------- scalarized node aggregation core (csr double-buffered) ----------------
__device__ __forceinline__ void agg_core(const ushort* __restrict__ T,
                                         const uint* __restrict__ csr,
                                         int beg, int end, int col,
                                         float& a0, float& a1) {
    if (beg >= end) return;
    int lane16 = threadIdx.x & 15;
    uint cur = csr[min(beg + lane16, end - 1)];
    for (int e = beg; e < end; e += 16) {
        uint nxt = 0;
        int en = e + 16;
        if (en < end) nxt = csr[min(en + lane16, end - 1)];
        uint v[16];
        float nn[16];
#pragma unroll
        for (int q = 0; q < 16; q++) {
            uint c = __builtin_amdgcn_readlane(cur, q);
            nn[q] = (e + q < end) ? q15f(c & 0x7FFFu) : 0.f;
            v[q] = *(const uint*)(T + (size_t)(c >> 15) * D + col);
        }
#pragma unroll
        for (int q = 0; q < 16; q++) {
            a0 = fmaf(nn[q], __uint_as_float(v[q] << 16), a0);
            a1 = fmaf(nn[q], __uint_as_float(v[q] & 0xffff0000u), a1);
        }
        cur = nxt;
    }
}

// ---------------- aggregation: Hbf[i] = relu( sum_j nrm*T[j] + di^2*T[i] + b ) ----------------
__global__ __launch_bounds__(256) void k_agg(const ushort* __restrict__ T,
                                             const float* __restrict__ dinv,
                                             const int* __restrict__ row_start,
                                             const uint* __restrict__ csr,
                                             const float* __restrict__ bias,
                                             ushort* __restrict__ out, int N) {
    int node = __builtin_amdgcn_readfirstlane(blockIdx.x * 4 + (threadIdx.x >> 6));
    if (node >= N) return;
    int lane = threadIdx.x & 63;
    int col = lane * 2;

    float di = dinv[node];
    uint vs = *(const uint*)(T + (size_t)node * D + col);
    float sw = di * di;
    float a0 = sw * __uint_as_float(vs << 16);
    float a1 = sw * __uint_as_float(vs & 0xffff0000u);

    agg_core(T, csr, row_start[node], row_start[node + 1], col, a0, a1);

    a0 = fmaxf(a0 + bias[col], 0.f);
    a1 = fmaxf(a1 + bias[col + 1], 0.f);
    ushort2 o; o.x = f2bf(a0); o.y = f2bf(a1);
    *(ushort2*)(out + (size_t)node * D + col) = o;
}

// ---------------- layer-3 aggregation + per-node head dot (no atomics) ----------------
__global__ __launch_bounds__(256) void k_agg_head(const ushort* __restrict__ T,
                                                  const float* __restrict__ dinv,
                                                  const int* __restrict__ row_start,
                                                  const uint* __restrict__ csr,
                                                  const float* __restrict__ bias,
                                                  const float* __restrict__ Wh,
                                                  float2* __restrict__ y, int N) {
    int node = __builtin_amdgcn_readfirstlane(blockIdx.x * 4 + (threadIdx.x >> 6));
    if (node >= N) return;
    int lane = threadIdx.x & 63;
    int col = lane * 2;

    float di = dinv[node];
    uint vs = *(const uint*)(T + (size_t)node * D + col);
    float sw = di * di;
    float a0 = sw * __uint_as_float(vs << 16);
    float a1 = sw * __uint_as_float(vs & 0xffff0000u);

    agg_core(T, csr, row_start[node], row_start[node + 1], col, a0, a1);

    a0 = fmaxf(a0 + bias[col], 0.f);
    a1 = fmaxf(a1 + bias[col + 1], 0.f);

    float p0 = a0 * Wh[col * 2 + 0] + a1 * Wh[(col + 1) * 2 + 0];
    float p1 = a0 * Wh[col * 2 + 1] + a1 * Wh[(col + 1) * 2 + 1];
#pragma unroll
    for (int off = 32; off > 0; off >>= 1) {
        p0 += __shfl_xor(p0, off);
        p1 += __shfl_xor(p1, off);
    }
    if (lane == 0) y[node] = make_float2(p0, p1);
}

// ---------------- per-graph segment mean + bias (batch sorted) ----------------
__global__ __launch_bounds__(256) void k_pool2(const float2* __restrict__ y,
                                               const int* __restrict__ batch, int N,
                                               const float* __restrict__ bh,
                                               float* __restrict__ out) {
    int g = blockIdx.x;
    int t = threadIdx.x;
    int lo = 0, hi = N;
    while (lo < hi) { int m = (lo + hi) >> 1; if (batch[m] < g) lo = m + 1; else hi = m; }
    int beg = lo;
    lo = 0; hi = N;
    while (lo < hi) { int m = (lo + hi) >> 1; if (batch[m] < g + 1) lo = m + 1; else hi = m; }
    int endi = lo;

    float s0 = 0.f, s1 = 0.f;
    for (int i = beg + t; i < endi; i += 256) {
        float2 v = y[i];
        s0 += v.x; s1 += v.y;
    }
    __shared__ float r0[256], r1[256];
    r0[t] = s0; r1[t] = s1;
    __syncthreads();
    for (int off = 128; off > 0; off >>= 1) {
        if (t < off) { r0[t] += r0[t + off]; r1[t] += r1[t + off]; }
        __syncthreads();
    }
    if (t == 0) {
        float cnt = (float)((endi - beg) > 0 ? (endi - beg) : 1);
        out[g * 2 + 0] = r0[0] / cnt + bh[0];
        out[g * 2 + 1] = r1[0] / cnt + bh[1];
    }
}

extern "C" void kernel_launch(void* const* d_in, const int* in_sizes, int n_in,
                              void* d_out, int out_size, void* d_ws, size_t ws_size,
                              hipStream_t stream) {
    const float* x   = (const float*)d_in[0];
    const int* eidx  = (const int*)d_in[1];
    const int* batch = (const int*)d_in[2];
    const float* W1 = (const float*)d_in[3];
    const float* b1 = (const float*)d_in[4];
    const float* W2 = (const float*)d_in[5];
    const float* b2 = (const float*)d_in[6];
    const float* W3 = (const float*)d_in[7];
    const float* b3 = (const float*)d_in[8];
    const float* Wh = (const float*)d_in[9];
    const float* bh = (const float*)d_in[10];

    int E = in_sizes[1] / 2;
    int N = in_sizes[2];
    int ngraphs = out_size / 2;
    const int* src = eidx;
    const int* dst = eidx + E;
    int nbk = (N + (1 << NB_SHIFT) - 1) >> NB_SHIFT;

    char* ws = (char*)d_ws;
    size_t off = 0;
    auto alloc = [&](size_t bytes) -> void* {
        void* p = ws + off;
        off = (off + bytes + 255) & ~(size_t)255;
        return p;
    };
    ushort* Hbf      = (ushort*)alloc((size_t)N * D * 2);
    ushort* T        = (ushort*)alloc((size_t)N * D * 2);
    ushort* Wf       = (ushort*)alloc(3 * 32768 * 2);
    float*  dinv     = (float*)alloc((size_t)N * 4);
    int*    row_start= (int*)alloc((size_t)(N + 1) * 4);
    int*    gcur     = (int*)alloc((size_t)nbk * 4);
    float2* y        = (float2*)alloc((size_t)N * 8);
    uint*   csr      = (uint*)alloc((size_t)E * 4);
    uint*   arena    = (uint*)alloc((size_t)nbk * BCAP * 4);
    (void)ws_size;

    k_wsplit3<<<384, 256, 0, stream>>>(W1, W2, W3, Wf, gcur, nbk);

    int gemm_grid = (N + 63) / 64;
    int agg_grid = (N + 3) / 4;
    int nA = (E + EPB - 1) / EPB;

    // fused: CSR bucket scatter (first nA blocks) || layer-1 GEMM
    k_build_gemm1<<<nA + gemm_grid, 256, 0, stream>>>(src, dst, E, nbk, gcur, arena,
                                                      nA, x, Wf, T, N);
    k_degB3<<<nbk, 256, 0, stream>>>(arena, gcur, nbk, N, E, dinv, row_start);
    k_bucketB<<<nbk, 256, 0, stream>>>(arena, gcur, row_start, dinv, N, csr);

    // layer 1 aggregation
    k_agg<<<agg_grid, 256, 0, stream>>>(T, dinv, row_start, csr, b1, Hbf, N);
    // layer 2
    k_gemm<false><<<gemm_grid, 256, 0, stream>>>(Hbf, Wf + 32768, T, N);
    k_agg<<<agg_grid, 256, 0, stream>>>(T, dinv, row_start, csr, b2, Hbf, N);
    // layer 3
    k_gemm<false><<<gemm_grid, 256, 0, stream>>>(Hbf, Wf + 65536, T, N);
    k_agg_head<<<agg_grid, 256, 0, stream>>>(T, dinv, row_start, csr, b3, Wh, y, N);
    k_pool2<<<ngraphs, 256, 0, stream>>>(y, batch, N, bh, (float*)d_out);
}